// Round 3
// baseline (6580.557 us; speedup 1.0000x reference)
//
#include <hip/hip_runtime.h>
#include <hip/hip_bf16.h>
#include <stdint.h>

// ---------- problem constants (fixed by setup_inputs) ----------
#define H_  2048      // hidden
#define I_  1024      // intermediate
#define E_  32        // experts
#define T_  8192      // tokens (4*2048)
#define A_  16384     // assignments (T*top_k)
#define MT_MAX 32     // max 128-row m-tiles per (expert,slot) segment

typedef unsigned short u16;
typedef u16  u16x8 __attribute__((ext_vector_type(8)));
typedef __bf16 bf16x8 __attribute__((ext_vector_type(8)));
typedef float f32x4 __attribute__((ext_vector_type(4)));

__device__ __forceinline__ u16 f2bf(float f) {
  union { float f; uint32_t u; } w; w.f = f;
  uint32_t r = (w.u + 0x7fffu + ((w.u >> 16) & 1u)) >> 16;
  return (u16)r;
}
__device__ __forceinline__ u16x8 cvt8(f32x4 a, f32x4 b) {
  u16x8 r;
  #pragma unroll
  for (int i = 0; i < 4; i++) { r[i] = f2bf(a[i]); r[i+4] = f2bf(b[i]); }
  return r;
}

// ---------- workspace layout (bytes), total 33,817,600 (~33.8 MB) ----------
// 0      : counts2[64] int   (index = expert*2 + slot)
// 256    : cursor2[64] int
// 512    : eoff[33]    int
// 768    : c0arr[32]   int
// 1024   : topk_e[A_]  int    -> 66560
// 66560  : topk_g[A_]  float  -> 132096
// 132096 : rows[A_]    int    -> 197632
// 197632 : gval[A_]    float  -> 263168
// 263168 : h[A_*I_]    bf16   -> 33817600

__global__ void k_zero(int* p) { p[threadIdx.x] = 0; }

// ---------- kernel 1: router (f32 in, f32 math) ----------
// block = 256 threads = 8 tokens x 32 experts. grid = T/8.
__global__ __launch_bounds__(256) void k_router(
    const float* __restrict__ x, const float* __restrict__ gw, const float* __restrict__ gb,
    int* __restrict__ counts2, int* __restrict__ topk_e, float* __restrict__ topk_g)
{
  int tid = threadIdx.x;
  int tt = tid >> 5;          // token within block
  int e  = tid & 31;          // expert
  int t  = blockIdx.x * 8 + tt;
  const float* xp = x  + (size_t)t * H_;
  const float* wp = gw + (size_t)e * H_;
  float acc = 0.f;
  for (int k = 0; k < H_; k += 8) {
    f32x4 x0 = *(const f32x4*)(xp + k);
    f32x4 x1 = *(const f32x4*)(xp + k + 4);
    f32x4 w0 = *(const f32x4*)(wp + k);
    f32x4 w1v = *(const f32x4*)(wp + k + 4);
    #pragma unroll
    for (int i = 0; i < 4; i++) acc += x0[i]*w0[i] + x1[i]*w1v[i];
  }
  float logit = acc + gb[e];
  // softmax over the 32-lane group
  float mx = logit;
  #pragma unroll
  for (int m = 16; m; m >>= 1) mx = fmaxf(mx, __shfl_xor(mx, m, 32));
  float p = __expf(logit - mx);
  float s = p;
  #pragma unroll
  for (int m = 16; m; m >>= 1) s += __shfl_xor(s, m, 32);
  float prob = p / s;
  // top-1 (tie -> lower index, matches jax top_k)
  float v1 = prob; int i1 = e;
  #pragma unroll
  for (int m = 16; m; m >>= 1) {
    float ov = __shfl_xor(v1, m, 32); int oi = __shfl_xor(i1, m, 32);
    if (ov > v1 || (ov == v1 && oi < i1)) { v1 = ov; i1 = oi; }
  }
  // top-2
  float v2 = (e == i1) ? -1.0f : prob; int i2 = e;
  #pragma unroll
  for (int m = 16; m; m >>= 1) {
    float ov = __shfl_xor(v2, m, 32); int oi = __shfl_xor(i2, m, 32);
    if (ov > v2 || (ov == v2 && oi < i2)) { v2 = ov; i2 = oi; }
  }
  if (e == 0) {
    topk_e[2*t]   = i1; topk_g[2*t]   = v1;   // slot 0
    topk_e[2*t+1] = i2; topk_g[2*t+1] = v2;   // slot 1
    atomicAdd(&counts2[2*i1 + 0], 1);
    atomicAdd(&counts2[2*i2 + 1], 1);
  }
}

// ---------- kernel 2: prefix scan ----------
__global__ void k_scan(const int* __restrict__ counts2, int* __restrict__ eoff,
                       int* __restrict__ c0arr) {
  if (threadIdx.x == 0) {
    int run = 0;
    for (int e = 0; e < E_; e++) {
      eoff[e] = run;
      c0arr[e] = counts2[2*e];
      run += counts2[2*e] + counts2[2*e+1];
    }
    eoff[E_] = run;
  }
}

// ---------- kernel 3: scatter, slot-ordered within each expert ----------
__global__ void k_scatter(const int* __restrict__ topk_e, const float* __restrict__ topk_g,
                          const int* __restrict__ eoff, const int* __restrict__ c0arr,
                          int* __restrict__ cursor2, int* __restrict__ rows, float* __restrict__ gval)
{
  int a = blockIdx.x * 256 + threadIdx.x;   // a < A_
  int t = a >> 1, slot = a & 1;
  int e = topk_e[a];
  int base = eoff[e] + (slot ? c0arr[e] : 0);
  int pos = base + atomicAdd(&cursor2[2*e + slot], 1);
  rows[pos] = t;
  gval[pos] = topk_g[a];
}

// ---------- kernel 4: fc1 grouped GEMM + swiglu (f32 in -> bf16 LDS -> MFMA) ----------
// block tile: 128 rows x 64 h-cols (=128 pre-cols, glu/lin de-interleaved)
// grid: x = E_*MT_MAX, y = I_/64 = 16
__global__ __launch_bounds__(256) void k_fc1(
    const float* __restrict__ x, const float* __restrict__ w1, const float* __restrict__ b1,
    const int* __restrict__ eoff, const int* __restrict__ rows, u16* __restrict__ h)
{
  int e  = blockIdx.x >> 5;          // / MT_MAX
  int mt = blockIdx.x & (MT_MAX-1);
  int seg0 = eoff[e], seg1 = eoff[e+1];
  int count = seg1 - seg0;
  if (mt * 128 >= count) return;
  int base_row = seg0 + mt * 128;
  int valid = count - mt * 128; if (valid > 128) valid = 128;
  int n0h = blockIdx.y * 64;

  __shared__ __align__(16) u16 As[128*64];
  __shared__ __align__(16) u16 Bg[64*64];
  __shared__ __align__(16) u16 Bl[64*64];
  __shared__ int toks[128];

  int tid = threadIdx.x;
  if (tid < 128) {
    int r = (tid < valid) ? tid : 0;
    toks[tid] = rows[base_row + r];
  }
  __syncthreads();

  const float* aptr[4];
  #pragma unroll
  for (int i = 0; i < 4; i++) {
    int c = tid + i*256; int r = c >> 3, cc = c & 7;
    aptr[i] = x + (size_t)toks[r] * H_ + cc*8;
  }
  const float* bgptr[2]; const float* blptr[2];
  #pragma unroll
  for (int i = 0; i < 2; i++) {
    int c = tid + i*256; int j = c >> 3, cc = c & 7;
    size_t rowg = (size_t)e * (2*I_) + 2*(n0h + j);   // even channel -> glu
    bgptr[i] = w1 + rowg * H_ + cc*8;
    blptr[i] = bgptr[i] + H_;                          // odd channel -> lin
  }

  int w = tid >> 6, lane = tid & 63;
  int wm = w >> 1, wn = w & 1;
  int lm = lane & 15, quad = lane >> 4;

  f32x4 zero = {0.f, 0.f, 0.f, 0.f};
  f32x4 accg[4][2], accl[4][2];
  #pragma unroll
  for (int i = 0; i < 4; i++)
    #pragma unroll
    for (int j = 0; j < 2; j++) { accg[i][j] = zero; accl[i][j] = zero; }

  for (int k0 = 0; k0 < H_; k0 += 64) {
    #pragma unroll
    for (int i = 0; i < 4; i++) {
      f32x4 v0 = *(const f32x4*)(aptr[i] + k0);
      f32x4 v1 = *(const f32x4*)(aptr[i] + k0 + 4);
      *(u16x8*)&As[(tid + i*256)*8] = cvt8(v0, v1);
    }
    #pragma unroll
    for (int i = 0; i < 2; i++) {
      int c = tid + i*256;
      f32x4 g0 = *(const f32x4*)(bgptr[i] + k0);
      f32x4 g1 = *(const f32x4*)(bgptr[i] + k0 + 4);
      f32x4 l0 = *(const f32x4*)(blptr[i] + k0);
      f32x4 l1 = *(const f32x4*)(blptr[i] + k0 + 4);
      *(u16x8*)&Bg[c*8] = cvt8(g0, g1);
      *(u16x8*)&Bl[c*8] = cvt8(l0, l1);
    }
    __syncthreads();
    #pragma unroll
    for (int kk = 0; kk < 64; kk += 32) {
      bf16x8 af[4], bgf[2], blf[2];
      #pragma unroll
      for (int i = 0; i < 4; i++)
        af[i] = *(const bf16x8*)&As[(wm*64 + i*16 + lm)*64 + kk + quad*8];
      #pragma unroll
      for (int j = 0; j < 2; j++) {
        int bro = (wn*32 + j*16 + lm)*64 + kk + quad*8;
        bgf[j] = *(const bf16x8*)&Bg[bro];
        blf[j] = *(const bf16x8*)&Bl[bro];
      }
      #pragma unroll
      for (int i = 0; i < 4; i++)
        #pragma unroll
        for (int j = 0; j < 2; j++) {
          accg[i][j] = __builtin_amdgcn_mfma_f32_16x16x32_bf16(af[i], bgf[j], accg[i][j], 0, 0, 0);
          accl[i][j] = __builtin_amdgcn_mfma_f32_16x16x32_bf16(af[i], blf[j], accl[i][j], 0, 0, 0);
        }
    }
    __syncthreads();
  }

  // epilogue: swiglu, store bf16 h
  #pragma unroll
  for (int i = 0; i < 4; i++) {
    #pragma unroll
    for (int j = 0; j < 2; j++) {
      int colh = n0h + wn*32 + j*16 + lm;
      float bg_ = b1[(size_t)e*(2*I_) + 2*colh];
      float bl_ = b1[(size_t)e*(2*I_) + 2*colh + 1];
      #pragma unroll
      for (int r = 0; r < 4; r++) {
        int rl = wm*64 + i*16 + quad*4 + r;
        if (rl < valid) {
          float g = accg[i][j][r] + bg_;
          float l = accl[i][j][r] + bl_;
          g = fminf(g, 7.0f);
          l = fminf(fmaxf(l, -7.0f), 7.0f);
          float hv = g * (1.0f / (1.0f + __expf(-1.702f * g))) * (l + 1.0f);
          h[(size_t)(base_row + rl) * I_ + colh] = f2bf(hv);
        }
      }
    }
  }
}

// ---------- kernel 5: fc2 grouped GEMM, gated, direct to f32 out ----------
// pass 0: slot-0 sub-segments, out = g*(acc+b2)   (each token exactly once)
// pass 1: slot-1 sub-segments, out += g*(acc+b2)  (sequential launch -> ordered)
// block tile: 128 rows x 128 cols, K = I_ = 1024
// grid: x = E_*MT_MAX, y = H_/128 = 16
__global__ __launch_bounds__(256) void k_fc2(
    const u16* __restrict__ h, const float* __restrict__ w2, const float* __restrict__ b2,
    const int* __restrict__ eoff, const int* __restrict__ c0arr,
    const int* __restrict__ rows, const float* __restrict__ gval,
    float* __restrict__ out, int pass)
{
  int e  = blockIdx.x >> 5;
  int mt = blockIdx.x & (MT_MAX-1);
  int seg0 = eoff[e];
  int c0 = c0arr[e];
  int ctot = eoff[e+1] - seg0;
  int base = seg0 + (pass ? c0 : 0);
  int cnt  = pass ? (ctot - c0) : c0;
  if (mt * 128 >= cnt) return;
  int base_row = base + mt * 128;
  int valid = cnt - mt * 128; if (valid > 128) valid = 128;
  int n0 = blockIdx.y * 128;

  __shared__ __align__(16) u16 As[128*64];
  __shared__ __align__(16) u16 Bs[128*64];

  int tid = threadIdx.x;
  const u16* aptr[4]; const float* bptr[4];
  #pragma unroll
  for (int i = 0; i < 4; i++) {
    int c = tid + i*256; int r = c >> 3, cc = c & 7;
    int ar = (r < valid) ? r : 0;
    aptr[i] = h  + (size_t)(base_row + ar) * I_ + cc*8;
    bptr[i] = w2 + ((size_t)e * H_ + n0 + r) * I_ + cc*8;
  }

  int w = tid >> 6, lane = tid & 63;
  int wm = w >> 1, wn = w & 1;
  int lm = lane & 15, quad = lane >> 4;

  f32x4 zero = {0.f, 0.f, 0.f, 0.f};
  f32x4 acc[4][4];
  #pragma unroll
  for (int i = 0; i < 4; i++)
    #pragma unroll
    for (int j = 0; j < 4; j++) acc[i][j] = zero;

  for (int k0 = 0; k0 < I_; k0 += 64) {
    #pragma unroll
    for (int i = 0; i < 4; i++) {
      int c = tid + i*256;
      u16x8 va = *(const u16x8*)(aptr[i] + k0);           // h already bf16
      f32x4 b0 = *(const f32x4*)(bptr[i] + k0);
      f32x4 b1v = *(const f32x4*)(bptr[i] + k0 + 4);
      *(u16x8*)&As[c*8] = va;
      *(u16x8*)&Bs[c*8] = cvt8(b0, b1v);
    }
    __syncthreads();
    #pragma unroll
    for (int kk = 0; kk < 64; kk += 32) {
      bf16x8 af[4], bf[4];
      #pragma unroll
      for (int i = 0; i < 4; i++)
        af[i] = *(const bf16x8*)&As[(wm*64 + i*16 + lm)*64 + kk + quad*8];
      #pragma unroll
      for (int j = 0; j < 4; j++)
        bf[j] = *(const bf16x8*)&Bs[(wn*64 + j*16 + lm)*64 + kk + quad*8];
      #pragma unroll
      for (int i = 0; i < 4; i++)
        #pragma unroll
        for (int j = 0; j < 4; j++)
          acc[i][j] = __builtin_amdgcn_mfma_f32_16x16x32_bf16(af[i], bf[j], acc[i][j], 0, 0, 0);
    }
    __syncthreads();
  }

  float bias[4];
  #pragma unroll
  for (int j = 0; j < 4; j++)
    bias[j] = b2[(size_t)e * H_ + n0 + wn*64 + j*16 + lm];

  #pragma unroll
  for (int i = 0; i < 4; i++) {
    #pragma unroll
    for (int r = 0; r < 4; r++) {
      int rl = wm*64 + i*16 + quad*4 + r;
      if (rl < valid) {
        int pos = base_row + rl;
        int t = rows[pos];
        float g = gval[pos];
        #pragma unroll
        for (int j = 0; j < 4; j++) {
          int col = n0 + wn*64 + j*16 + lm;
          size_t oidx = (size_t)t * H_ + col;
          float val = g * (acc[i][j][r] + bias[j]);
          if (pass)
            out[oidx] = out[oidx] + val;
          else
            out[oidx] = val;
        }
      }
    }
  }
}

// ---------- launch ----------
extern "C" void kernel_launch(void* const* d_in, const int* in_sizes, int n_in,
                              void* d_out, int out_size, void* d_ws, size_t ws_size,
                              hipStream_t stream) {
  const float* x  = (const float*)d_in[0];
  const float* gw = (const float*)d_in[1];
  const float* gb = (const float*)d_in[2];
  const float* w1 = (const float*)d_in[3];
  const float* b1 = (const float*)d_in[4];
  const float* w2 = (const float*)d_in[5];
  const float* b2 = (const float*)d_in[6];
  float* out = (float*)d_out;

  char* ws = (char*)d_ws;
  int*   counts2 = (int*)(ws + 0);
  int*   cursor2 = (int*)(ws + 256);
  int*   eoff    = (int*)(ws + 512);
  int*   c0arr   = (int*)(ws + 768);
  int*   topk_e  = (int*)(ws + 1024);
  float* topk_g  = (float*)(ws + 66560);
  int*   rows    = (int*)(ws + 132096);
  float* gval    = (float*)(ws + 197632);
  u16*   hbuf    = (u16*)(ws + 263168);

  k_zero<<<1, 128, 0, stream>>>(counts2);   // counts2 + cursor2 (contiguous 128 ints)
  k_router<<<T_/8, 256, 0, stream>>>(x, gw, gb, counts2, topk_e, topk_g);
  k_scan<<<1, 32, 0, stream>>>(counts2, eoff, c0arr);
  k_scatter<<<A_/256, 256, 0, stream>>>(topk_e, topk_g, eoff, c0arr, cursor2, rows, gval);
  k_fc1<<<dim3(E_*MT_MAX, I_/64), 256, 0, stream>>>(x, w1, b1, eoff, rows, hbuf);
  k_fc2<<<dim3(E_*MT_MAX, H_/128), 256, 0, stream>>>(hbuf, w2, b2, eoff, c0arr, rows, gval, out, 0);
  k_fc2<<<dim3(E_*MT_MAX, H_/128), 256, 0, stream>>>(hbuf, w2, b2, eoff, c0arr, rows, gval, out, 1);
}